// Round 3
// baseline (9239.994 us; speedup 1.0000x reference)
//
#include <hip/hip_runtime.h>
#include <hip/hip_bf16.h>
#include <stdint.h>

// RNN: h_t = relu(xs_t @ W_ih^T + h_{t-1} @ W_hh^T); ys = (h_seq @ W_out^T) -> [B,T,O]
// R3: recurrence uses fine-grained producer/consumer flags (no global barrier).
// hseq layout is slice-major: h[t][jb 128][b 64][16 j] bf16, so each producer block's
// output is a cacheline-exclusive 2KB block. 256 blocks = 2 b-halves x 128 j-slices;
// the two b-half groups decouple completely. Consumers read h via relaxed agent-scope
// atomic loads (cache-bypassing to LLC); producers release with the validated
// syncthreads -> threadfence -> release-store pattern.

#define TT 512
#define BB 64
#define NIN 1024
#define NH 2048
#define NOUT 1024

typedef __attribute__((ext_vector_type(8))) short bf8;
typedef __attribute__((ext_vector_type(4))) float f4;
typedef __attribute__((ext_vector_type(4))) unsigned int u4;
typedef __attribute__((ext_vector_type(2))) unsigned long long ull2;

static __device__ __forceinline__ unsigned short f2bf(float f) {
  __hip_bfloat16 h = __float2bfloat16(f);
  return __builtin_bit_cast(unsigned short, h);
}
static __device__ __forceinline__ float bf2f(unsigned short v) {
  return __bfloat162float(__builtin_bit_cast(__hip_bfloat16, v));
}
static __device__ __forceinline__ u4 pack8(const float* f) {
  u4 r;
#pragma unroll
  for (int i = 0; i < 4; ++i) {
    unsigned lo = f2bf(f[2 * i]);
    unsigned hi = f2bf(f[2 * i + 1]);
    r[i] = lo | (hi << 16);
  }
  return r;
}

// sliced-layout element index for (m-row, k/j-col): h[t=m>>6][col>>4][m&63][col&15]
static __device__ __forceinline__ size_t sl_idx(int m, int col) {
  return (((size_t)(m >> 6) * 128 + (col >> 4)) << 10) + (size_t)(m & 63) * 16 + (col & 15);
}

// ---------------- generic C[M,N] = A[M,K] * B[N,K]^T (bf16 MFMA) ----------------
// ABF: A is bf16 in sliced layout. else A is f32 row-major.
// TRANS: store f32 out[b][t][n]; else store bf16 into sliced layout.
template <bool ABF, bool TRANS>
__global__ void gemm_bt(const void* __restrict__ Av, const float* __restrict__ Bw,
                        void* __restrict__ Cv, int M, int N, int K) {
  constexpr int BM = 128, BN = 128, BK = 32;
  __shared__ u4 As[BM * 4];
  __shared__ u4 Bs[BN * 4];
  const int nt = N / BN;
  const int mi = (int)blockIdx.x / nt;
  const int ni = (int)blockIdx.x % nt;
  const int m0 = mi * BM, n0 = ni * BN;
  const int t = threadIdx.x;
  const int l = t & 63, w = t >> 6, wr = w >> 1, wc = w & 1;
  const int lr = l & 15, lq = l >> 4;

  f4 acc[4][4] = {};

  const int srow = t >> 1;
  const int sc0 = (t & 1) * 2;

  for (int kt = 0; kt < K; kt += BK) {
    if (ABF) {
      const unsigned short* A = (const unsigned short*)Av;
#pragma unroll
      for (int cc = 0; cc < 2; ++cc) {
        int c = sc0 + cc;
        u4 v = *(const u4*)(A + sl_idx(m0 + srow, kt + c * 8));
        As[srow * 4 + (c ^ ((srow ^ (srow >> 2)) & 3))] = v;
      }
    } else {
      const float* A = (const float*)Av;
#pragma unroll
      for (int cc = 0; cc < 2; ++cc) {
        int c = sc0 + cc;
        const float* p = A + (size_t)(m0 + srow) * K + kt + c * 8;
        float4 v0 = *(const float4*)p;
        float4 v1 = *(const float4*)(p + 4);
        float f[8] = {v0.x, v0.y, v0.z, v0.w, v1.x, v1.y, v1.z, v1.w};
        As[srow * 4 + (c ^ ((srow ^ (srow >> 2)) & 3))] = pack8(f);
      }
    }
#pragma unroll
    for (int cc = 0; cc < 2; ++cc) {
      int c = sc0 + cc;
      const float* p = Bw + (size_t)(n0 + srow) * K + kt + c * 8;
      float4 v0 = *(const float4*)p;
      float4 v1 = *(const float4*)(p + 4);
      float f[8] = {v0.x, v0.y, v0.z, v0.w, v1.x, v1.y, v1.z, v1.w};
      Bs[srow * 4 + (c ^ ((srow ^ (srow >> 2)) & 3))] = pack8(f);
    }
    __syncthreads();

    bf8 a[4], b[4];
#pragma unroll
    for (int i = 0; i < 4; ++i) {
      int ra = wr * 64 + i * 16 + lr;
      a[i] = __builtin_bit_cast(bf8, As[ra * 4 + (lq ^ ((ra ^ (ra >> 2)) & 3))]);
      int rb = wc * 64 + i * 16 + lr;
      b[i] = __builtin_bit_cast(bf8, Bs[rb * 4 + (lq ^ ((rb ^ (rb >> 2)) & 3))]);
    }
#pragma unroll
    for (int i = 0; i < 4; ++i)
#pragma unroll
      for (int j = 0; j < 4; ++j)
        acc[i][j] = __builtin_amdgcn_mfma_f32_16x16x32_bf16(a[i], b[j], acc[i][j], 0, 0, 0);
    __syncthreads();
  }

  if (TRANS) {
    float* C = (float*)Cv;
#pragma unroll
    for (int i = 0; i < 4; ++i)
#pragma unroll
      for (int j = 0; j < 4; ++j)
#pragma unroll
        for (int r = 0; r < 4; ++r) {
          int m = m0 + wr * 64 + i * 16 + lq * 4 + r;
          int n = n0 + wc * 64 + j * 16 + lr;
          C[(size_t)(m & 63) * (TT * NOUT) + (size_t)(m >> 6) * NOUT + n] = acc[i][j][r];
        }
  } else {
    unsigned short* C = (unsigned short*)Cv;
#pragma unroll
    for (int i = 0; i < 4; ++i)
#pragma unroll
      for (int j = 0; j < 4; ++j)
#pragma unroll
        for (int r = 0; r < 4; ++r) {
          int m = m0 + wr * 64 + i * 16 + lq * 4 + r;
          int n = n0 + wc * 64 + j * 16 + lr;
          C[sl_idx(m, n)] = f2bf(acc[i][j][r]);
        }
  }
}

// ---------------- persistent recurrence kernel (flag-flow, no global barrier) ----
// 256 blocks: blockIdx.x = bh*128 + jb. Block owns output slice (rows bh*32..+32,
// cols jb*16..+16). 16 waves = bg(2, 16-row groups) x kg(8, 256-k eighths).
// flags[bh*128+jb] = number of h-steps this producer has published (monotone).
__global__ __launch_bounds__(1024, 4) void rnn_recur(unsigned short* __restrict__ hseq,
                                                     const float* __restrict__ Whh,
                                                     unsigned* __restrict__ flags) {
  __shared__ u4 Wl[16 * 256];             // 64 KiB: [j_local][k-chunk of 8], chunk ^ (j&7)
  __shared__ float red[7 * 2 * 16 * 17];  // 15 KiB: [kg-1][bg][row16][j16+pad]
  const int t = threadIdx.x;
  const int jb = (int)blockIdx.x & 127;
  const int bh = (int)blockIdx.x >> 7;
  const int j0 = jb * 16;

  // one-time: W_hh j-slice -> swizzled LDS (both b-half blocks of a jb load the same slice)
  {
    const int jl = t >> 6;
    const int c0 = (t & 63) * 4;
#pragma unroll
    for (int c = 0; c < 4; ++c) {
      int cc = c0 + c;
      const float* p = Whh + (size_t)(j0 + jl) * NH + cc * 8;
      float4 v0 = *(const float4*)p;
      float4 v1 = *(const float4*)(p + 4);
      float f[8] = {v0.x, v0.y, v0.z, v0.w, v1.x, v1.y, v1.z, v1.w};
      Wl[jl * 256 + (cc ^ (jl & 7))] = pack8(f);
    }
  }

  const int l = t & 63, w = t >> 6;
  const int lr = l & 15, lq = l >> 4;
  const int bg = w & 1, kg = w >> 1;
  const int row = bh * 32 + bg * 16 + lr;  // b-row of this lane's A fragment

  float pre[4] = {0.f, 0.f, 0.f, 0.f};

  // t = 0: h_0 = relu(P_0) for our 32 rows of our slice; prefetch P_1
  if (kg == 0) {
#pragma unroll
    for (int r = 0; r < 4; ++r) {
      int bl = bg * 16 + lq * 4 + r;
      size_t e0 = ((size_t)jb << 10) + (size_t)(bh * 32 + bl) * 16 + lr;
      unsigned short v = hseq[e0];
      hseq[e0] = (v & 0x8000u) ? (unsigned short)0 : v;
      pre[r] = bf2f(hseq[(((size_t)128 + jb) << 10) + (size_t)(bh * 32 + bl) * 16 + lr]);
    }
  }
  __syncthreads();
  if (t == 0) {
    __threadfence();
    __hip_atomic_store(flags + blockIdx.x, 1u, __ATOMIC_RELEASE, __HIP_MEMORY_SCOPE_AGENT);
  }

  const unsigned long long* hb = (const unsigned long long*)hseq;

  for (int ts = 1; ts < TT; ++ts) {
    // wait for the 16 producer slices this wave consumes (h_{ts-1} ready <=> flag >= ts)
    {
      const unsigned* fp = flags + bh * 128 + kg * 16 + lr;
      long spins = 0;
      for (;;) {
        unsigned fv = __hip_atomic_load(fp, __ATOMIC_RELAXED, __HIP_MEMORY_SCOPE_AGENT);
        if (__ballot(fv >= (unsigned)ts) == ~0ull) break;
        __builtin_amdgcn_s_sleep(1);
        if (++spins > (1L << 22)) break;  // hang safety; never hit when logic is correct
      }
    }
    asm volatile("" ::: "memory");  // keep data loads below the flag spin

    // a-frags: 16 x 8B cache-bypassing loads (k-eighth kg, rows = own b-row)
    unsigned long long av[16];
    const size_t tb = (size_t)(ts - 1) * 128;
#pragma unroll
    for (int u = 0; u < 8; ++u) {
      int k0 = kg * 256 + u * 32;
      int s = (k0 >> 4) + (lq >> 1);
      size_t e = ((tb + s) << 10) + (size_t)row * 16 + (lq & 1) * 8;
      const unsigned long long* p = hb + (e >> 2);
      av[2 * u] = __hip_atomic_load(p, __ATOMIC_RELAXED, __HIP_MEMORY_SCOPE_AGENT);
      av[2 * u + 1] = __hip_atomic_load(p + 1, __ATOMIC_RELAXED, __HIP_MEMORY_SCOPE_AGENT);
    }

    f4 acc0 = {}, acc1 = {};
#pragma unroll
    for (int u = 0; u < 8; ++u) {
      ull2 tv;
      tv[0] = av[2 * u];
      tv[1] = av[2 * u + 1];
      bf8 af = __builtin_bit_cast(bf8, tv);
      int c = kg * 32 + u * 4 + lq;
      bf8 bf = __builtin_bit_cast(bf8, Wl[lr * 256 + (c ^ (lr & 7))]);
      if (u & 1)
        acc1 = __builtin_amdgcn_mfma_f32_16x16x32_bf16(af, bf, acc1, 0, 0, 0);
      else
        acc0 = __builtin_amdgcn_mfma_f32_16x16x32_bf16(af, bf, acc0, 0, 0, 0);
    }
    f4 a2 = acc0 + acc1;

    if (kg) {
      const int base = ((kg - 1) * 2 + bg) * (16 * 17);
#pragma unroll
      for (int r = 0; r < 4; ++r) red[base + (lq * 4 + r) * 17 + lr] = a2[r];
    }
    __syncthreads();

    if (kg == 0) {
#pragma unroll
      for (int r = 0; r < 4; ++r) {
        int ro = (lq * 4 + r) * 17 + lr;
        float s_ = a2[r] + pre[r];
#pragma unroll
        for (int q = 1; q < 8; ++q) s_ += red[((q - 1) * 2 + bg) * (16 * 17) + ro];
        int bl = bg * 16 + lq * 4 + r;
        size_t e = (((size_t)ts * 128 + jb) << 10) + (size_t)(bh * 32 + bl) * 16 + lr;
        hseq[e] = (s_ > 0.f) ? f2bf(s_) : (unsigned short)0;
      }
    }
    __syncthreads();  // all h-stores drained to L2 (compiler emits vmcnt(0) before barrier)

    if (t == 0) {
      __threadfence();  // flush L1/L2 -> LLC so bypass-readers see fresh data
      __hip_atomic_store(flags + blockIdx.x, (unsigned)(ts + 1), __ATOMIC_RELEASE,
                         __HIP_MEMORY_SCOPE_AGENT);
    }
    // prefetch P for step ts+1 (own slice, own rows; only ever touched by this block)
    if (kg == 0 && ts + 1 < TT) {
#pragma unroll
      for (int r = 0; r < 4; ++r) {
        int bl = bg * 16 + lq * 4 + r;
        pre[r] = bf2f(hseq[(((size_t)(ts + 1) * 128 + jb) << 10) + (size_t)(bh * 32 + bl) * 16 + lr]);
      }
    }
  }
}

__global__ void kinit(unsigned* f) { f[threadIdx.x] = 0u; }

extern "C" void kernel_launch(void* const* d_in, const int* in_sizes, int n_in,
                              void* d_out, int out_size, void* d_ws, size_t ws_size,
                              hipStream_t stream) {
  const float* xs = (const float*)d_in[0];
  const float* Wih = (const float*)d_in[1];
  const float* Whh = (const float*)d_in[2];
  const float* Wout = (const float*)d_in[3];

  unsigned short* hseq = (unsigned short*)d_ws;  // sliced [TT][128][64][16] bf16 = 128 MiB
  unsigned* flags = (unsigned*)((char*)d_ws + (size_t)TT * BB * NH * 2);  // 256 x u32

  kinit<<<1, 256, 0, stream>>>(flags);

  // phase 1: P = xs @ W_ih^T -> bf16 sliced layout
  gemm_bt<false, false><<<(TT * BB / 128) * (NH / 128), 256, 0, stream>>>(
      (const void*)xs, Wih, (void*)hseq, TT * BB, NH, NIN);

  // phase 2: recurrence (flag-flow)
  rnn_recur<<<256, 1024, 0, stream>>>(hseq, Whh, flags);

  // phase 3: out[b][t][o] = h_seq @ W_out^T
  gemm_bt<true, true><<<(TT * BB / 128) * (NOUT / 128), 256, 0, stream>>>(
      (const void*)hseq, Wout, d_out, TT * BB, NOUT, NH);
}

// Round 4
// 4890.647 us; speedup vs baseline: 1.8893x; 1.8893x over previous
//
#include <hip/hip_runtime.h>
#include <hip/hip_bf16.h>
#include <stdint.h>

// RNN: h_t = relu(xs_t @ W_ih^T + h_{t-1} @ W_hh^T); ys = (h_seq @ W_out^T) -> [B,T,O]
// R4: fence-free producer/consumer flow. h-stores are write-through-to-LLC agent-scope
// atomic stores (no __threadfence / buffer_wbl2 on the critical path). A single writer
// wave per block does the cross-kg reduction (via double-buffered LDS), +P, relu, pack,
// write-through store, same-wave vmcnt(0), then flag store. Consumers unchanged from R3:
// relaxed agent-scope bypass loads gated by per-producer monotone flags.

#define TT 512
#define BB 64
#define NIN 1024
#define NH 2048
#define NOUT 1024

typedef __attribute__((ext_vector_type(8))) short bf8;
typedef __attribute__((ext_vector_type(4))) float f4;
typedef __attribute__((ext_vector_type(4))) unsigned int u4;
typedef __attribute__((ext_vector_type(2))) unsigned long long ull2;

static __device__ __forceinline__ unsigned short f2bf(float f) {
  __hip_bfloat16 h = __float2bfloat16(f);
  return __builtin_bit_cast(unsigned short, h);
}
static __device__ __forceinline__ float bf2f(unsigned short v) {
  return __bfloat162float(__builtin_bit_cast(__hip_bfloat16, v));
}
static __device__ __forceinline__ u4 pack8(const float* f) {
  u4 r;
#pragma unroll
  for (int i = 0; i < 4; ++i) {
    unsigned lo = f2bf(f[2 * i]);
    unsigned hi = f2bf(f[2 * i + 1]);
    r[i] = lo | (hi << 16);
  }
  return r;
}

// sliced-layout element index for (m-row, k/j-col): h[t=m>>6][col>>4][m&63][col&15]
static __device__ __forceinline__ size_t sl_idx(int m, int col) {
  return (((size_t)(m >> 6) * 128 + (col >> 4)) << 10) + (size_t)(m & 63) * 16 + (col & 15);
}

// ---------------- generic C[M,N] = A[M,K] * B[N,K]^T (bf16 MFMA) ----------------
template <bool ABF, bool TRANS>
__global__ void gemm_bt(const void* __restrict__ Av, const float* __restrict__ Bw,
                        void* __restrict__ Cv, int M, int N, int K) {
  constexpr int BM = 128, BN = 128, BK = 32;
  __shared__ u4 As[BM * 4];
  __shared__ u4 Bs[BN * 4];
  const int nt = N / BN;
  const int mi = (int)blockIdx.x / nt;
  const int ni = (int)blockIdx.x % nt;
  const int m0 = mi * BM, n0 = ni * BN;
  const int t = threadIdx.x;
  const int l = t & 63, w = t >> 6, wr = w >> 1, wc = w & 1;
  const int lr = l & 15, lq = l >> 4;

  f4 acc[4][4] = {};

  const int srow = t >> 1;
  const int sc0 = (t & 1) * 2;

  for (int kt = 0; kt < K; kt += BK) {
    if (ABF) {
      const unsigned short* A = (const unsigned short*)Av;
#pragma unroll
      for (int cc = 0; cc < 2; ++cc) {
        int c = sc0 + cc;
        u4 v = *(const u4*)(A + sl_idx(m0 + srow, kt + c * 8));
        As[srow * 4 + (c ^ ((srow ^ (srow >> 2)) & 3))] = v;
      }
    } else {
      const float* A = (const float*)Av;
#pragma unroll
      for (int cc = 0; cc < 2; ++cc) {
        int c = sc0 + cc;
        const float* p = A + (size_t)(m0 + srow) * K + kt + c * 8;
        float4 v0 = *(const float4*)p;
        float4 v1 = *(const float4*)(p + 4);
        float f[8] = {v0.x, v0.y, v0.z, v0.w, v1.x, v1.y, v1.z, v1.w};
        As[srow * 4 + (c ^ ((srow ^ (srow >> 2)) & 3))] = pack8(f);
      }
    }
#pragma unroll
    for (int cc = 0; cc < 2; ++cc) {
      int c = sc0 + cc;
      const float* p = Bw + (size_t)(n0 + srow) * K + kt + c * 8;
      float4 v0 = *(const float4*)p;
      float4 v1 = *(const float4*)(p + 4);
      float f[8] = {v0.x, v0.y, v0.z, v0.w, v1.x, v1.y, v1.z, v1.w};
      Bs[srow * 4 + (c ^ ((srow ^ (srow >> 2)) & 3))] = pack8(f);
    }
    __syncthreads();

    bf8 a[4], b[4];
#pragma unroll
    for (int i = 0; i < 4; ++i) {
      int ra = wr * 64 + i * 16 + lr;
      a[i] = __builtin_bit_cast(bf8, As[ra * 4 + (lq ^ ((ra ^ (ra >> 2)) & 3))]);
      int rb = wc * 64 + i * 16 + lr;
      b[i] = __builtin_bit_cast(bf8, Bs[rb * 4 + (lq ^ ((rb ^ (rb >> 2)) & 3))]);
    }
#pragma unroll
    for (int i = 0; i < 4; ++i)
#pragma unroll
      for (int j = 0; j < 4; ++j)
        acc[i][j] = __builtin_amdgcn_mfma_f32_16x16x32_bf16(a[i], b[j], acc[i][j], 0, 0, 0);
    __syncthreads();
  }

  if (TRANS) {
    float* C = (float*)Cv;
#pragma unroll
    for (int i = 0; i < 4; ++i)
#pragma unroll
      for (int j = 0; j < 4; ++j)
#pragma unroll
        for (int r = 0; r < 4; ++r) {
          int m = m0 + wr * 64 + i * 16 + lq * 4 + r;
          int n = n0 + wc * 64 + j * 16 + lr;
          C[(size_t)(m & 63) * (TT * NOUT) + (size_t)(m >> 6) * NOUT + n] = acc[i][j][r];
        }
  } else {
    unsigned short* C = (unsigned short*)Cv;
#pragma unroll
    for (int i = 0; i < 4; ++i)
#pragma unroll
      for (int j = 0; j < 4; ++j)
#pragma unroll
        for (int r = 0; r < 4; ++r) {
          int m = m0 + wr * 64 + i * 16 + lq * 4 + r;
          int n = n0 + wc * 64 + j * 16 + lr;
          C[sl_idx(m, n)] = f2bf(acc[i][j][r]);
        }
  }
}

// ---------------- persistent recurrence kernel (fence-free flag-flow) ------------
// 256 blocks: blockIdx.x = bh*128 + jb. Block produces slice (rows bh*32..+32, cols
// jb*16..+16). 16 waves = bg(2) x kg(8). All waves write MFMA partials into
// double-buffered red LDS; wave 0 alone reduces, adds P, relus, write-through-stores
// h, waits vmcnt(0) (same wave), and publishes the flag. No fences anywhere.
__global__ __launch_bounds__(1024, 4) void rnn_recur(unsigned short* __restrict__ hseq,
                                                     const float* __restrict__ Whh,
                                                     unsigned* __restrict__ flags) {
  __shared__ u4 Wl[16 * 256];          // 64 KiB: [j_local][k-chunk of 8], chunk ^ (j&7)
  __shared__ float red[2][8][32][20];  // 40 KiB: [buf][kg][local row][j 16 pad 20]
  __shared__ unsigned tok[8];          // per-kg observed step token (bg0 -> bg1 mirror)
  const int t = threadIdx.x;
  const int jb = (int)blockIdx.x & 127;
  const int bh = (int)blockIdx.x >> 7;
  const int j0 = jb * 16;

  // one-time: W_hh j-slice -> swizzled LDS
  {
    const int jl = t >> 6;
    const int c0 = (t & 63) * 4;
#pragma unroll
    for (int c = 0; c < 4; ++c) {
      int cc = c0 + c;
      const float* p = Whh + (size_t)(j0 + jl) * NH + cc * 8;
      float4 v0 = *(const float4*)p;
      float4 v1 = *(const float4*)(p + 4);
      float f[8] = {v0.x, v0.y, v0.z, v0.w, v1.x, v1.y, v1.z, v1.w};
      Wl[jl * 256 + (cc ^ (jl & 7))] = pack8(f);
    }
  }
  if (t < 8) tok[t] = 0;

  const int l = t & 63, w = t >> 6;
  const int lr = l & 15, lq = l >> 4;
  const int bg = w & 1, kg = w >> 1;
  const int row = bh * 32 + bg * 16 + lr;

  // writer-wave (wave 0) lane roles: 64 lanes = 32 local rows x 2 j-halves
  const int wrow = l >> 1;
  const int wjh = l & 1;
  const size_t woff = (size_t)(bh * 32 + wrow) * 16 + wjh * 8;

  u4 pre = {};  // next-step P (8 bf16), writer wave only

  __syncthreads();  // Wl + tok ready

  if (w == 0) {
    // h_0 = relu(P_0), write-through; then flag=1; prefetch P_1
    size_t e0 = ((size_t)jb << 10) + woff;
    u4 p0 = *(const u4*)(hseq + e0);
    u4 hv;
#pragma unroll
    for (int i = 0; i < 4; ++i) {
      unsigned lo = p0[i] & 0xffffu, hi = p0[i] >> 16;
      if (lo & 0x8000u) lo = 0;
      if (hi & 0x8000u) hi = 0;
      hv[i] = lo | (hi << 16);
    }
    ull2 w2 = __builtin_bit_cast(ull2, hv);
    unsigned long long* dst = (unsigned long long*)(hseq + e0);
    __hip_atomic_store(dst, w2[0], __ATOMIC_RELAXED, __HIP_MEMORY_SCOPE_AGENT);
    __hip_atomic_store(dst + 1, w2[1], __ATOMIC_RELAXED, __HIP_MEMORY_SCOPE_AGENT);
    asm volatile("s_waitcnt vmcnt(0)" ::: "memory");
    if (l == 0)
      __hip_atomic_store(flags + blockIdx.x, 1u, __ATOMIC_RELAXED, __HIP_MEMORY_SCOPE_AGENT);
    pre = *(const u4*)(hseq + (((size_t)128 + jb) << 10) + woff);
  }

  const unsigned long long* hb = (const unsigned long long*)hseq;

  for (int ts = 1; ts < TT; ++ts) {
    // wait for the 16 producer slices this wave's k-eighth consumes
    if (bg == 0) {
      const unsigned* fp = flags + bh * 128 + kg * 16 + lr;
      long spins = 0;
      for (;;) {
        unsigned fv = __hip_atomic_load(fp, __ATOMIC_RELAXED, __HIP_MEMORY_SCOPE_AGENT);
        if (__ballot(fv >= (unsigned)ts) == ~0ull) break;
        __builtin_amdgcn_s_sleep(1);
        if (++spins > (1L << 22)) break;  // hang safety
      }
      if (l == 0)
        __hip_atomic_store(&tok[kg], (unsigned)ts, __ATOMIC_RELAXED,
                           __HIP_MEMORY_SCOPE_WORKGROUP);
    } else {
      long spins = 0;
      while (__hip_atomic_load(&tok[kg], __ATOMIC_RELAXED, __HIP_MEMORY_SCOPE_WORKGROUP) <
             (unsigned)ts) {
        __builtin_amdgcn_s_sleep(1);
        if (++spins > (1L << 22)) break;
      }
    }
    asm volatile("" ::: "memory");  // keep data loads below the spin

    // a-frags: 16 x 8B bypass loads (k-eighth kg, own b-row)
    unsigned long long av[16];
    const size_t tb = (size_t)(ts - 1) * 128;
#pragma unroll
    for (int u = 0; u < 8; ++u) {
      int k0 = kg * 256 + u * 32;
      int s = (k0 >> 4) + (lq >> 1);
      size_t e = ((tb + s) << 10) + (size_t)row * 16 + (lq & 1) * 8;
      const unsigned long long* p = hb + (e >> 2);
      av[2 * u] = __hip_atomic_load(p, __ATOMIC_RELAXED, __HIP_MEMORY_SCOPE_AGENT);
      av[2 * u + 1] = __hip_atomic_load(p + 1, __ATOMIC_RELAXED, __HIP_MEMORY_SCOPE_AGENT);
    }

    f4 acc0 = {}, acc1 = {};
#pragma unroll
    for (int u = 0; u < 8; ++u) {
      ull2 tv;
      tv[0] = av[2 * u];
      tv[1] = av[2 * u + 1];
      bf8 af = __builtin_bit_cast(bf8, tv);
      int c = kg * 32 + u * 4 + lq;
      bf8 bfr = __builtin_bit_cast(bf8, Wl[lr * 256 + (c ^ (lr & 7))]);
      if (u & 1)
        acc1 = __builtin_amdgcn_mfma_f32_16x16x32_bf16(af, bfr, acc1, 0, 0, 0);
      else
        acc0 = __builtin_amdgcn_mfma_f32_16x16x32_bf16(af, bfr, acc0, 0, 0, 0);
    }
    f4 a2 = acc0 + acc1;

    const int buf = ts & 1;
#pragma unroll
    for (int r = 0; r < 4; ++r) red[buf][kg][bg * 16 + lq * 4 + r][lr] = a2[r];
    __syncthreads();

    if (w == 0) {
      f4 s0 = {}, s1 = {};
#pragma unroll
      for (int q = 0; q < 8; ++q) {
        const float* rp = &red[buf][q][wrow][wjh * 8];
        s0 += *(const f4*)rp;
        s1 += *(const f4*)(rp + 4);
      }
      float sf[8] = {s0[0], s0[1], s0[2], s0[3], s1[0], s1[1], s1[2], s1[3]};
#pragma unroll
      for (int i = 0; i < 4; ++i) {
        sf[2 * i] += bf2f((unsigned short)(pre[i] & 0xffffu));
        sf[2 * i + 1] += bf2f((unsigned short)(pre[i] >> 16));
      }
#pragma unroll
      for (int i = 0; i < 8; ++i) sf[i] = sf[i] > 0.f ? sf[i] : 0.f;
      u4 hv = pack8(sf);
      ull2 w2 = __builtin_bit_cast(ull2, hv);
      size_t eo = (((size_t)ts * 128 + jb) << 10) + woff;
      unsigned long long* dst = (unsigned long long*)(hseq + eo);
      __hip_atomic_store(dst, w2[0], __ATOMIC_RELAXED, __HIP_MEMORY_SCOPE_AGENT);
      __hip_atomic_store(dst + 1, w2[1], __ATOMIC_RELAXED, __HIP_MEMORY_SCOPE_AGENT);
      asm volatile("s_waitcnt vmcnt(0)" ::: "memory");  // same-wave drain: stores at LLC
      if (l == 0)
        __hip_atomic_store(flags + blockIdx.x, (unsigned)(ts + 1), __ATOMIC_RELAXED,
                           __HIP_MEMORY_SCOPE_AGENT);
      if (ts + 1 < TT)
        pre = *(const u4*)(hseq + (((size_t)(ts + 1) * 128 + jb) << 10) + woff);
    }
  }
}

__global__ void kinit(unsigned* f) { f[threadIdx.x] = 0u; }

extern "C" void kernel_launch(void* const* d_in, const int* in_sizes, int n_in,
                              void* d_out, int out_size, void* d_ws, size_t ws_size,
                              hipStream_t stream) {
  const float* xs = (const float*)d_in[0];
  const float* Wih = (const float*)d_in[1];
  const float* Whh = (const float*)d_in[2];
  const float* Wout = (const float*)d_in[3];

  unsigned short* hseq = (unsigned short*)d_ws;  // sliced [TT][128][64][16] bf16 = 128 MiB
  unsigned* flags = (unsigned*)((char*)d_ws + (size_t)TT * BB * NH * 2);  // 256 x u32

  kinit<<<1, 256, 0, stream>>>(flags);

  // phase 1: P = xs @ W_ih^T -> bf16 sliced layout
  gemm_bt<false, false><<<(TT * BB / 128) * (NH / 128), 256, 0, stream>>>(
      (const void*)xs, Wih, (void*)hseq, TT * BB, NH, NIN);

  // phase 2: recurrence (fence-free flag-flow)
  rnn_recur<<<256, 1024, 0, stream>>>(hseq, Whh, flags);

  // phase 3: out[b][t][o] = h_seq @ W_out^T
  gemm_bt<true, true><<<(TT * BB / 128) * (NOUT / 128), 256, 0, stream>>>(
      (const void*)hseq, Wout, d_out, TT * BB, NOUT, NH);
}

// Round 5
// 3929.676 us; speedup vs baseline: 2.3513x; 1.2445x over previous
//
#include <hip/hip_runtime.h>
#include <hip/hip_bf16.h>
#include <stdint.h>

// RNN: h_t = relu(xs_t @ W_ih^T + h_{t-1} @ W_hh^T); ys = (h_seq @ W_out^T) -> [B,T,O]
// R5: (a) a-frag loads are 8x global_load_dwordx4 sc0 sc1 in ONE asm block with a single
// vmcnt(0) drain -> guaranteed 8-deep MLP to the LLC (R4's atomic loads were serialized,
// VGPR=52 proves it). (b) Writer epilogue split across two waves (one per 16-row half)
// with per-half sub-flags (512 flags). (c) tok LDS mirror dropped - all waves poll global.

#define TT 512
#define BB 64
#define NIN 1024
#define NH 2048
#define NOUT 1024

typedef __attribute__((ext_vector_type(8))) short bf8;
typedef __attribute__((ext_vector_type(4))) float f4;
typedef __attribute__((ext_vector_type(4))) unsigned int u4;
typedef __attribute__((ext_vector_type(2))) unsigned long long ull2;

static __device__ __forceinline__ unsigned short f2bf(float f) {
  __hip_bfloat16 h = __float2bfloat16(f);
  return __builtin_bit_cast(unsigned short, h);
}
static __device__ __forceinline__ float bf2f(unsigned short v) {
  return __bfloat162float(__builtin_bit_cast(__hip_bfloat16, v));
}
static __device__ __forceinline__ u4 pack8(const float* f) {
  u4 r;
#pragma unroll
  for (int i = 0; i < 4; ++i) {
    unsigned lo = f2bf(f[2 * i]);
    unsigned hi = f2bf(f[2 * i + 1]);
    r[i] = lo | (hi << 16);
  }
  return r;
}

// sliced-layout element index for (m-row, k/j-col): h[t=m>>6][col>>4][m&63][col&15]
static __device__ __forceinline__ size_t sl_idx(int m, int col) {
  return (((size_t)(m >> 6) * 128 + (col >> 4)) << 10) + (size_t)(m & 63) * 16 + (col & 15);
}

// ---------------- generic C[M,N] = A[M,K] * B[N,K]^T (bf16 MFMA) ----------------
template <bool ABF, bool TRANS>
__global__ void gemm_bt(const void* __restrict__ Av, const float* __restrict__ Bw,
                        void* __restrict__ Cv, int M, int N, int K) {
  constexpr int BM = 128, BN = 128, BK = 32;
  __shared__ u4 As[BM * 4];
  __shared__ u4 Bs[BN * 4];
  const int nt = N / BN;
  const int mi = (int)blockIdx.x / nt;
  const int ni = (int)blockIdx.x % nt;
  const int m0 = mi * BM, n0 = ni * BN;
  const int t = threadIdx.x;
  const int l = t & 63, w = t >> 6, wr = w >> 1, wc = w & 1;
  const int lr = l & 15, lq = l >> 4;

  f4 acc[4][4] = {};

  const int srow = t >> 1;
  const int sc0 = (t & 1) * 2;

  for (int kt = 0; kt < K; kt += BK) {
    if (ABF) {
      const unsigned short* A = (const unsigned short*)Av;
#pragma unroll
      for (int cc = 0; cc < 2; ++cc) {
        int c = sc0 + cc;
        u4 v = *(const u4*)(A + sl_idx(m0 + srow, kt + c * 8));
        As[srow * 4 + (c ^ ((srow ^ (srow >> 2)) & 3))] = v;
      }
    } else {
      const float* A = (const float*)Av;
#pragma unroll
      for (int cc = 0; cc < 2; ++cc) {
        int c = sc0 + cc;
        const float* p = A + (size_t)(m0 + srow) * K + kt + c * 8;
        float4 v0 = *(const float4*)p;
        float4 v1 = *(const float4*)(p + 4);
        float f[8] = {v0.x, v0.y, v0.z, v0.w, v1.x, v1.y, v1.z, v1.w};
        As[srow * 4 + (c ^ ((srow ^ (srow >> 2)) & 3))] = pack8(f);
      }
    }
#pragma unroll
    for (int cc = 0; cc < 2; ++cc) {
      int c = sc0 + cc;
      const float* p = Bw + (size_t)(n0 + srow) * K + kt + c * 8;
      float4 v0 = *(const float4*)p;
      float4 v1 = *(const float4*)(p + 4);
      float f[8] = {v0.x, v0.y, v0.z, v0.w, v1.x, v1.y, v1.z, v1.w};
      Bs[srow * 4 + (c ^ ((srow ^ (srow >> 2)) & 3))] = pack8(f);
    }
    __syncthreads();

    bf8 a[4], b[4];
#pragma unroll
    for (int i = 0; i < 4; ++i) {
      int ra = wr * 64 + i * 16 + lr;
      a[i] = __builtin_bit_cast(bf8, As[ra * 4 + (lq ^ ((ra ^ (ra >> 2)) & 3))]);
      int rb = wc * 64 + i * 16 + lr;
      b[i] = __builtin_bit_cast(bf8, Bs[rb * 4 + (lq ^ ((rb ^ (rb >> 2)) & 3))]);
    }
#pragma unroll
    for (int i = 0; i < 4; ++i)
#pragma unroll
      for (int j = 0; j < 4; ++j)
        acc[i][j] = __builtin_amdgcn_mfma_f32_16x16x32_bf16(a[i], b[j], acc[i][j], 0, 0, 0);
    __syncthreads();
  }

  if (TRANS) {
    float* C = (float*)Cv;
#pragma unroll
    for (int i = 0; i < 4; ++i)
#pragma unroll
      for (int j = 0; j < 4; ++j)
#pragma unroll
        for (int r = 0; r < 4; ++r) {
          int m = m0 + wr * 64 + i * 16 + lq * 4 + r;
          int n = n0 + wc * 64 + j * 16 + lr;
          C[(size_t)(m & 63) * (TT * NOUT) + (size_t)(m >> 6) * NOUT + n] = acc[i][j][r];
        }
  } else {
    unsigned short* C = (unsigned short*)Cv;
#pragma unroll
    for (int i = 0; i < 4; ++i)
#pragma unroll
      for (int j = 0; j < 4; ++j)
#pragma unroll
        for (int r = 0; r < 4; ++r) {
          int m = m0 + wr * 64 + i * 16 + lq * 4 + r;
          int n = n0 + wc * 64 + j * 16 + lr;
          C[sl_idx(m, n)] = f2bf(acc[i][j][r]);
        }
  }
}

// ---------------- persistent recurrence kernel (fence-free flag-flow) ------------
// 256 blocks: blockIdx.x = bh*128 + jb. Block produces slice (rows bh*32..+32, cols
// jb*16..+16). 16 waves = bg(2) x kg(8). Partials -> double-buffered red LDS; waves 0/1
// (kg==0, bg==w) each reduce + store their own 16-row half, drain, publish sub-flag
// flags[block*2+bg]. Consumers poll the 16 sub-flags (own bg) of the producers covering
// their k-eighth, then pull data with 8x dwordx4 sc0 sc1 in one asm (full MLP).
__global__ __launch_bounds__(1024, 4) void rnn_recur(unsigned short* __restrict__ hseq,
                                                     const float* __restrict__ Whh,
                                                     unsigned* __restrict__ flags) {
  __shared__ u4 Wl[16 * 256];          // 64 KiB: [j_local][k-chunk of 8], chunk ^ (j&7)
  __shared__ float red[2][8][32][20];  // 40 KiB: [buf][kg][local row][j 16 pad 20]
  const int t = threadIdx.x;
  const int jb = (int)blockIdx.x & 127;
  const int bh = (int)blockIdx.x >> 7;
  const int j0 = jb * 16;

  // one-time: W_hh j-slice -> swizzled LDS
  {
    const int jl = t >> 6;
    const int c0 = (t & 63) * 4;
#pragma unroll
    for (int c = 0; c < 4; ++c) {
      int cc = c0 + c;
      const float* p = Whh + (size_t)(j0 + jl) * NH + cc * 8;
      float4 v0 = *(const float4*)p;
      float4 v1 = *(const float4*)(p + 4);
      float f[8] = {v0.x, v0.y, v0.z, v0.w, v1.x, v1.y, v1.z, v1.w};
      Wl[jl * 256 + (cc ^ (jl & 7))] = pack8(f);
    }
  }

  const int l = t & 63, w = t >> 6;
  const int lr = l & 15, lq = l >> 4;
  const int bg = w & 1, kg = w >> 1;
  const int row = bh * 32 + bg * 16 + lr;

  // writer-wave lane roles (waves 0/1): 64 lanes = 16 local rows x 4 j-quarters (4 elems)
  const int wrowL = bg * 16 + (l >> 2);  // local row 0..31 (w<2 => bg==w)
  const int wjq = l & 3;
  const size_t woff = (size_t)(bh * 32 + wrowL) * 16 + wjq * 4;

  unsigned long long pre = 0;  // next-step P (4 bf16), writer waves only

  __syncthreads();  // Wl ready

  if (w < 2) {
    // h_0 = relu(P_0) (sign-bit relu exact in bf16), write-through; flag=1; prefetch P_1
    size_t e0 = ((size_t)jb << 10) + woff;
    unsigned long long p0 = *(const unsigned long long*)(hseq + e0);
    unsigned long long hv = 0;
#pragma unroll
    for (int i = 0; i < 4; ++i) {
      unsigned long long x = (p0 >> (16 * i)) & 0xffffull;
      if (!(x & 0x8000ull)) hv |= x << (16 * i);
    }
    __hip_atomic_store((unsigned long long*)(hseq + e0), hv, __ATOMIC_RELAXED,
                       __HIP_MEMORY_SCOPE_AGENT);
    asm volatile("s_waitcnt vmcnt(0)" ::: "memory");
    if (l == 0)
      __hip_atomic_store(flags + ((int)blockIdx.x * 2 + w), 1u, __ATOMIC_RELAXED,
                         __HIP_MEMORY_SCOPE_AGENT);
    pre = *(const unsigned long long*)(hseq + (((size_t)128 + jb) << 10) + woff);
  }

  for (int ts = 1; ts < TT; ++ts) {
    // wait for the 16 producer sub-slices (own bg) covering this wave's k-eighth
    {
      const unsigned* fp = flags + ((bh * 128 + kg * 16 + lr) * 2 + bg);
      long spins = 0;
      for (;;) {
        unsigned fv = __hip_atomic_load(fp, __ATOMIC_RELAXED, __HIP_MEMORY_SCOPE_AGENT);
        if (__ballot(fv >= (unsigned)ts) == ~0ull) break;
        __builtin_amdgcn_s_sleep(1);
        if (++spins > (1L << 22)) break;  // hang safety
      }
    }
    asm volatile("" ::: "memory");  // keep data loads below the spin

    // a-frags: 8 x 16B LLC loads, all in flight, one drain — single asm block
    const size_t tb = (size_t)(ts - 1) * 128;
    const size_t rowoff = (size_t)row * 16 + (lq & 1) * 8;
    const size_t sbase = tb + kg * 16 + (lq >> 1);
    unsigned long long ad[8];
#pragma unroll
    for (int u = 0; u < 8; ++u)
      ad[u] = (unsigned long long)(uintptr_t)(hseq + (((sbase + 2 * u) << 10) + rowoff));
    u4 av[8];
    asm volatile(
        "global_load_dwordx4 %0, %8, off sc0 sc1\n\t"
        "global_load_dwordx4 %1, %9, off sc0 sc1\n\t"
        "global_load_dwordx4 %2, %10, off sc0 sc1\n\t"
        "global_load_dwordx4 %3, %11, off sc0 sc1\n\t"
        "global_load_dwordx4 %4, %12, off sc0 sc1\n\t"
        "global_load_dwordx4 %5, %13, off sc0 sc1\n\t"
        "global_load_dwordx4 %6, %14, off sc0 sc1\n\t"
        "global_load_dwordx4 %7, %15, off sc0 sc1\n\t"
        "s_waitcnt vmcnt(0)"
        : "=&v"(av[0]), "=&v"(av[1]), "=&v"(av[2]), "=&v"(av[3]),
          "=&v"(av[4]), "=&v"(av[5]), "=&v"(av[6]), "=&v"(av[7])
        : "v"(ad[0]), "v"(ad[1]), "v"(ad[2]), "v"(ad[3]),
          "v"(ad[4]), "v"(ad[5]), "v"(ad[6]), "v"(ad[7])
        : "memory");

    f4 acc0 = {}, acc1 = {};
#pragma unroll
    for (int u = 0; u < 8; ++u) {
      bf8 af = __builtin_bit_cast(bf8, av[u]);
      int c = kg * 32 + u * 4 + lq;
      bf8 bfr = __builtin_bit_cast(bf8, Wl[lr * 256 + (c ^ (lr & 7))]);
      if (u & 1)
        acc1 = __builtin_amdgcn_mfma_f32_16x16x32_bf16(af, bfr, acc1, 0, 0, 0);
      else
        acc0 = __builtin_amdgcn_mfma_f32_16x16x32_bf16(af, bfr, acc0, 0, 0, 0);
    }
    f4 a2 = acc0 + acc1;

    const int buf = ts & 1;
#pragma unroll
    for (int r = 0; r < 4; ++r) red[buf][kg][bg * 16 + lq * 4 + r][lr] = a2[r];
    __syncthreads();

    if (w < 2) {
      f4 s = {};
#pragma unroll
      for (int q = 0; q < 8; ++q) s += *(const f4*)&red[buf][q][wrowL][wjq * 4];
      float sf[4];
#pragma unroll
      for (int i = 0; i < 4; ++i) {
        float v = s[i] + bf2f((unsigned short)((pre >> (16 * i)) & 0xffffull));
        sf[i] = v > 0.f ? v : 0.f;
      }
      unsigned lo = (unsigned)f2bf(sf[0]) | ((unsigned)f2bf(sf[1]) << 16);
      unsigned hi = (unsigned)f2bf(sf[2]) | ((unsigned)f2bf(sf[3]) << 16);
      unsigned long long hv = (unsigned long long)lo | ((unsigned long long)hi << 32);
      size_t eo = (((size_t)ts * 128 + jb) << 10) + woff;
      __hip_atomic_store((unsigned long long*)(hseq + eo), hv, __ATOMIC_RELAXED,
                         __HIP_MEMORY_SCOPE_AGENT);
      asm volatile("s_waitcnt vmcnt(0)" ::: "memory");  // same-wave drain: stores at LLC
      if (l == 0)
        __hip_atomic_store(flags + ((int)blockIdx.x * 2 + w), (unsigned)(ts + 1),
                           __ATOMIC_RELAXED, __HIP_MEMORY_SCOPE_AGENT);
      if (ts + 1 < TT)
        pre = *(const unsigned long long*)(hseq + (((size_t)(ts + 1) * 128 + jb) << 10) + woff);
    }
  }
}

__global__ void kinit(unsigned* f) { f[threadIdx.x] = 0u; }

extern "C" void kernel_launch(void* const* d_in, const int* in_sizes, int n_in,
                              void* d_out, int out_size, void* d_ws, size_t ws_size,
                              hipStream_t stream) {
  const float* xs = (const float*)d_in[0];
  const float* Wih = (const float*)d_in[1];
  const float* Whh = (const float*)d_in[2];
  const float* Wout = (const float*)d_in[3];

  unsigned short* hseq = (unsigned short*)d_ws;  // sliced [TT][128][64][16] bf16 = 128 MiB
  unsigned* flags = (unsigned*)((char*)d_ws + (size_t)TT * BB * NH * 2);  // 512 x u32

  kinit<<<1, 512, 0, stream>>>(flags);

  // phase 1: P = xs @ W_ih^T -> bf16 sliced layout
  gemm_bt<false, false><<<(TT * BB / 128) * (NH / 128), 256, 0, stream>>>(
      (const void*)xs, Wih, (void*)hseq, TT * BB, NH, NIN);

  // phase 2: recurrence (fence-free flag-flow, MLP loads)
  rnn_recur<<<256, 1024, 0, stream>>>(hseq, Whh, flags);

  // phase 3: out[b][t][o] = h_seq @ W_out^T
  gemm_bt<true, true><<<(TT * BB / 128) * (NOUT / 128), 256, 0, stream>>>(
      (const void*)hseq, Wout, d_out, TT * BB, NOUT, NH);
}